// Round 1
// baseline (880.430 us; speedup 1.0000x reference)
//
#include <hip/hip_runtime.h>
#include <stdint.h>

#define B_ 4
#define H_ 640
#define W_ 640
#define C_ 64
#define K_ 2048
#define N_ (H_ * W_)
#define NBINS 131072        // 2^17 bins of (bits >> 13)
#define CAP 8192            // candidate cap per batch (power of 2 for bitonic)

// ---- workspace layout (bytes) ----
#define OFF_BITS   0
#define SZ_BITS    (B_ * N_ * 4)                 // 6,553,600
#define OFF_HIST   (OFF_BITS + SZ_BITS)          // 6,553,600
#define SZ_HIST    (B_ * NBINS * 4)              // 2,097,152
#define OFF_CCNT   (OFF_HIST + SZ_HIST)          // 8,650,752
#define SZ_CCNT    16
#define OFF_BSTAR  (OFF_CCNT + SZ_CCNT)          // 8,650,768
#define SZ_BSTAR   16
#define OFF_CAND   (OFF_BSTAR + SZ_BSTAR)        // 8,650,784 (16B aligned)
#define SZ_CAND    (B_ * CAP * 8)                // 262,144
#define OFF_TOPK   (OFF_CAND + SZ_CAND)          // 8,912,928
#define SZ_TOPK    (B_ * K_ * 4)                 // 32,768

// Kernel 1: 3x3 NMS (-inf pad semantics) + histogram of nonzero value bits
__global__ void nms_hist_kernel(const float* __restrict__ p,
                                uint32_t* __restrict__ bits_out,
                                uint32_t* __restrict__ hist) {
    int t = blockIdx.x * blockDim.x + threadIdx.x;
    if (t >= B_ * N_) return;
    int b = t / N_;
    int i = t - b * N_;
    int y = i / W_;
    int x = i - y * W_;
    const float* pb = p + (size_t)b * N_;
    float c = pb[i];
    float m = c;
    #pragma unroll
    for (int dy = -1; dy <= 1; dy++) {
        int yy = y + dy;
        if (yy < 0 || yy >= H_) continue;
        #pragma unroll
        for (int dx = -1; dx <= 1; dx++) {
            int xx = x + dx;
            if (xx < 0 || xx >= W_) continue;
            m = fmaxf(m, pb[yy * W_ + xx]);
        }
    }
    float nms = (c == m) ? c : 0.0f;
    uint32_t bits = __float_as_uint(nms);   // nms >= 0 -> monotone
    bits_out[t] = bits;
    if (bits) atomicAdd(&hist[b * NBINS + (bits >> 13)], 1u);
}

// Kernel 2: per-batch, find bin b* such that count(bins >= b*) >= K > count(bins > b*)
__global__ void findbin_kernel(const uint32_t* __restrict__ hist,
                               uint32_t* __restrict__ binstar) {
    int b = blockIdx.x;
    const uint32_t* h = hist + b * NBINS;
    __shared__ uint32_t part[256];
    int tid = threadIdx.x;               // 256 threads, 512 bins each
    uint32_t s = 0;
    int base = tid * 512;
    for (int j = 0; j < 512; j++) s += h[base + j];
    part[tid] = s;
    __syncthreads();
    if (tid == 0) {
        uint32_t cum = 0;
        int sel = -1;
        for (int t2 = 255; t2 >= 0; t2--) {
            if (cum + part[t2] >= (uint32_t)K_) { sel = t2; break; }
            cum += part[t2];
        }
        uint32_t bstar = 0;
        if (sel >= 0) {
            uint32_t c2 = cum;
            for (int j = 511; j >= 0; j--) {
                uint32_t bin = sel * 512 + j;
                c2 += h[bin];
                if (c2 >= (uint32_t)K_) { bstar = bin; break; }
            }
        }
        binstar[b] = bstar;
    }
}

// Kernel 3: collect candidate keys (value bits desc, index asc tie-break)
__global__ void collect_kernel(const uint32_t* __restrict__ bits_in,
                               const uint32_t* __restrict__ binstar,
                               uint32_t* __restrict__ ccnt,
                               unsigned long long* __restrict__ cand) {
    int t = blockIdx.x * blockDim.x + threadIdx.x;
    if (t >= B_ * N_) return;
    int b = t / N_;
    int i = t - b * N_;
    uint32_t bits = bits_in[t];
    if (bits && (bits >> 13) >= binstar[b]) {
        uint32_t pos = atomicAdd(&ccnt[b], 1u);
        if (pos < CAP) {
            cand[(size_t)b * CAP + pos] =
                ((unsigned long long)bits << 32) | (unsigned long long)(0xFFFFFFFFu - (uint32_t)i);
        }
    }
}

// Kernel 4: per-batch bitonic sort (descending) of <= CAP keys, emit top-K indices
__global__ __launch_bounds__(1024) void sort_kernel(const unsigned long long* __restrict__ cand,
                                                    const uint32_t* __restrict__ ccnt,
                                                    uint32_t* __restrict__ topk) {
    __shared__ unsigned long long sh[CAP];   // 64 KB
    int b = blockIdx.x;
    int tid = threadIdx.x;
    uint32_t cnt = ccnt[b];
    if (cnt > CAP) cnt = CAP;
    const unsigned long long* cb = cand + (size_t)b * CAP;
    for (int j = tid; j < CAP; j += 1024) sh[j] = (j < (int)cnt) ? cb[j] : 0ULL;
    __syncthreads();
    for (unsigned k = 2; k <= CAP; k <<= 1) {
        for (unsigned j = k >> 1; j > 0; j >>= 1) {
            for (unsigned t = tid; t < CAP / 2; t += 1024) {
                unsigned i = (t / j) * (2 * j) + (t % j);
                unsigned ixj = i + j;
                unsigned long long a = sh[i], c = sh[ixj];
                bool dirDesc = ((i & k) == 0);
                // descending overall: in desc blocks put larger first
                if (dirDesc ? (a < c) : (a > c)) { sh[i] = c; sh[ixj] = a; }
            }
            __syncthreads();
        }
    }
    for (int k2 = tid; k2 < K_; k2 += 1024) {
        topk[b * K_ + k2] = 0xFFFFFFFFu - (uint32_t)(sh[k2] & 0xFFFFFFFFull);
    }
}

// Kernel 5: one wave (64 lanes) per keypoint: subpixel softmax refine + bilinear sample
__global__ void final_kernel(const uint32_t* __restrict__ topk,
                             const float* __restrict__ probs,
                             const float* __restrict__ logits,
                             const float* __restrict__ fm,
                             float* __restrict__ out) {
    int gtid = blockIdx.x * blockDim.x + threadIdx.x;
    int wid = gtid >> 6;          // one wave per keypoint
    int lane = threadIdx.x & 63;
    if (wid >= B_ * K_) return;
    int b = wid / K_;
    int k = wid - b * K_;
    int idx = (int)topk[b * K_ + k];
    int h = idx / W_;
    int w = idx - h * W_;

    // 3x3 logit patch, zero-padded borders, temp 0.5 softmax
    const float* lg = logits + (size_t)b * N_;
    float v[9];
    #pragma unroll
    for (int di = 0; di < 3; di++) {
        #pragma unroll
        for (int dj = 0; dj < 3; dj++) {
            int yy = h + di - 1, xx = w + dj - 1;
            float val = (yy >= 0 && yy < H_ && xx >= 0 && xx < W_) ? lg[yy * W_ + xx] : 0.0f;
            v[di * 3 + dj] = val * 2.0f;   // / SUBPIXEL_TEMP
        }
    }
    float m = v[0];
    #pragma unroll
    for (int j = 1; j < 9; j++) m = fmaxf(m, v[j]);
    float e[9], s = 0.0f;
    #pragma unroll
    for (int j = 0; j < 9; j++) { e[j] = __expf(v[j] - m); s += e[j]; }
    float inv = 1.0f / s;
    float dx = 0.0f, dy = 0.0f;
    #pragma unroll
    for (int di = 0; di < 3; di++) {
        #pragma unroll
        for (int dj = 0; dj < 3; dj++) {
            float pr = e[di * 3 + dj] * inv;
            dx += pr * (float)(dj - 1);
            dy += pr * (float)(di - 1);
        }
    }
    float x = (float)w + dx;
    float y = (float)h + dy;

    // bilinear sample coords (clipped)
    float xc = fminf(fmaxf(x, 0.0f), (float)(W_ - 1));
    float yc = fminf(fmaxf(y, 0.0f), (float)(H_ - 1));
    float x0f = floorf(xc), y0f = floorf(yc);
    float wx = xc - x0f, wy = yc - y0f;
    int x0 = (int)x0f, y0 = (int)y0f;
    int x1 = min(x0 + 1, W_ - 1), y1 = min(y0 + 1, H_ - 1);
    float w00 = (1.0f - wx) * (1.0f - wy);
    float w01 = wx * (1.0f - wy);
    float w10 = (1.0f - wx) * wy;
    float w11 = wx * wy;
    int i00 = y0 * W_ + x0, i01 = y0 * W_ + x1, i10 = y1 * W_ + x0, i11 = y1 * W_ + x1;

    float* ob = out + ((size_t)b * K_ + k) * (C_ + 3);

    // lane l samples feature channel l
    const float* ch = fm + ((size_t)b * C_ + lane) * N_;
    float sv = ch[i00] * w00 + ch[i01] * w01 + ch[i10] * w10 + ch[i11] * w11;
    ob[3 + lane] = sv;

    if (lane == 0) {
        const float* pp = probs + (size_t)b * N_;
        float sp = pp[i00] * w00 + pp[i01] * w01 + pp[i10] * w10 + pp[i11] * w11;
        ob[0] = x;
        ob[1] = y;
        ob[2] = sp;
    }
}

extern "C" void kernel_launch(void* const* d_in, const int* in_sizes, int n_in,
                              void* d_out, int out_size, void* d_ws, size_t ws_size,
                              hipStream_t stream) {
    const float* probs  = (const float*)d_in[0];
    const float* logits = (const float*)d_in[1];
    const float* fm     = (const float*)d_in[2];
    float* out = (float*)d_out;

    char* ws = (char*)d_ws;
    uint32_t* bits   = (uint32_t*)(ws + OFF_BITS);
    uint32_t* hist   = (uint32_t*)(ws + OFF_HIST);
    uint32_t* ccnt   = (uint32_t*)(ws + OFF_CCNT);
    uint32_t* bstar  = (uint32_t*)(ws + OFF_BSTAR);
    unsigned long long* cand = (unsigned long long*)(ws + OFF_CAND);
    uint32_t* topk   = (uint32_t*)(ws + OFF_TOPK);

    // zero hist + candidate counters (ws is poisoned 0xAA before each launch)
    hipMemsetAsync((void*)hist, 0, SZ_HIST + SZ_CCNT, stream);

    int total = B_ * N_;
    int blk = 256;
    nms_hist_kernel<<<(total + blk - 1) / blk, blk, 0, stream>>>(probs, bits, hist);
    findbin_kernel<<<B_, 256, 0, stream>>>(hist, bstar);
    collect_kernel<<<(total + blk - 1) / blk, blk, 0, stream>>>(bits, bstar, ccnt, cand);
    sort_kernel<<<B_, 1024, 0, stream>>>(cand, ccnt, topk);

    int waves = B_ * K_;                    // one wave per keypoint
    int threads = waves * 64;
    final_kernel<<<(threads + 255) / 256, 256, 0, stream>>>(topk, probs, logits, fm, out);
}